// Round 8
// baseline (151.782 us; speedup 1.0000x reference)
//
#include <hip/hip_runtime.h>
#include <stdint.h>

// ---------------------------------------------------------------------------
// MultiAttentionHead: B=4 S=1024 E=1024 H=16 D=64, fp32 in/out.
// R19: R18 BUGFIX. R18 (in-register P, 32x32 MFMA, 1 barrier/iter) failed
// absmax=0.96: the epilogue O-combine used float4 LDS stores across q-ROWS
// (stride-64 data) -- wrote 4 memory-consecutive lanes instead, racing
// adjacent lanes. Fix: scalar osh[r*64+l] stores/loads (epilogue-only,
// lanes contiguous, conflict-free). All R18 structure kept:
//   8 waves = 4 q-blocks x 2 t-halves; S^T = K*Q via 32x32x16 (C: col=q,
//   row=(r&3)+8*(r>>2)+4*lh = t); P stays in registers: exp2 -> f2h pack
//   -> 8x shfl_xor(32)+cndmask rebuilds PV A-frags; PV 4x MFMA32;
//   ONE __syncthreads/iter (P-publish barrier deleted).
// R17/R16: reverted V-tail+mlive (intra-K-loop branch = m141-class 2x).
// R15: QBLK=128 (512 thr), K/V staged once per 128 q. R13: k_proj Q/K
// dead-row block skip. R12: swapped QK^T. Carried: R1 XOR swizzle,
// R4 static softmax, R7 dbuf, R8 LDS epilogue + direct V^T, R10 all-fp16,
// R11 batch-balance remap. R9/R14/R16: loops reject dbuf/counted-vmcnt/
// intra-loop branches -- compiler's own schedule is the asset.
// ---------------------------------------------------------------------------

using u16     = unsigned short;
using half8   = __attribute__((ext_vector_type(8))) _Float16;
using floatx4 = __attribute__((ext_vector_type(4))) float;
using f32x16  = __attribute__((ext_vector_type(16))) float;

#define MFMA16(a, b, c) __builtin_amdgcn_mfma_f32_16x16x32_f16(a, b, c, 0, 0, 0)
#define MFMA32(a, b, c) __builtin_amdgcn_mfma_f32_32x32x16_f16(a, b, c, 0, 0, 0)

__device__ __forceinline__ u16 f2h(float f) {  // f32 -> f16 bits (RTN)
  _Float16 h = (_Float16)f; u16 u; __builtin_memcpy(&u, &h, 2); return u;
}

// async global->LDS DMA, 16B per lane. LDS dest must be wave-uniform base +
// lane*16 (no per-lane scatter) -- so bank swizzles permute the GLOBAL src.
__device__ __forceinline__ void async_cp16(void* lds, const void* g) {
  __builtin_amdgcn_global_load_lds(
      (__attribute__((address_space(1))) uint32_t*)(uintptr_t)g,
      (__attribute__((address_space(3))) uint32_t*)(uint32_t)(uintptr_t)lds,
      16, 0, 0);
}

// ---------------------------------------------------------------------------
// 1) prep (fused): blocks [0,4096): x -> f16 (block 0 zeroes vsum);
//    blocks [4096,7168): transpose W -> WT[n][k] f16.
// ---------------------------------------------------------------------------
__global__ void k_prep(const float* __restrict__ x, u16* __restrict__ xh,
                       const float* __restrict__ w0, const float* __restrict__ w1,
                       const float* __restrict__ w2,
                       u16* __restrict__ o0, u16* __restrict__ o1,
                       u16* __restrict__ o2, float* __restrict__ vsum) {
  __shared__ float t[32][33];
  const int bx = blockIdx.x;
  if (bx < 4096) {
    int i = (bx * 256 + threadIdx.x) * 4;
    float4 v = *(const float4*)(x + i);
    ushort4 hv;
    hv.x = f2h(v.x);
    hv.y = f2h(v.y);
    hv.z = f2h(v.z);
    hv.w = f2h(v.w);
    *(ushort4*)(xh + i) = hv;
    if (bx == 0) {  // zero vsum (4096 floats) for k_proj's atomics
      float4 z = {0.f, 0.f, 0.f, 0.f};
#pragma unroll
      for (int e = 0; e < 4; e++) ((float4*)vsum)[threadIdx.x * 4 + e] = z;
    }
    return;
  }
  const int id = bx - 4096;                 // 0..3071
  const int z = id >> 10, rem = id & 1023;
  const float* W = z == 0 ? w0 : (z == 1 ? w1 : w2);
  u16* oh = z == 0 ? o0 : (z == 1 ? o1 : o2);
  const int kb = (rem & 31) * 32, nb = (rem >> 5) * 32;
  const int tx = threadIdx.x & 31, ty = threadIdx.x >> 5;
  for (int r = ty; r < 32; r += 8) t[r][tx] = W[(kb + r) * 1024 + nb + tx];
  __syncthreads();
  for (int r = ty; r < 32; r += 8)
    oh[(nb + r) * 1024 + kb + tx] = f2h(t[tx][r]);
}

// ---------------------------------------------------------------------------
// 2) projection GEMM: C[4096][1024] = xh @ Wh + b, fp16 single pass,
//    128x128 tile, BK=64, 2-barrier K-loop (R9: dbuf regresses here).
//    LDS 32 KB staging / 34.8 KB epilogue tile -> 4 blocks/CU. Epilogue
//    stages C through LDS ([128][136]) for 16B stores. z=0/1 -> q/k f16 in
//    [B][H][S][D] (q pre-scaled by 0.125*log2e); z=2 -> V^T f16 + vsum.
//    R13: z=0/1 blocks whose 128 s-rows are all >= len[b] early-return.
// ---------------------------------------------------------------------------
__launch_bounds__(256, 4)
__global__ void k_proj(const u16* __restrict__ xh,
                       const u16* __restrict__ wqT, const u16* __restrict__ wkT,
                       const u16* __restrict__ wvT,
                       const float* __restrict__ bq, const float* __restrict__ bk,
                       const float* __restrict__ bv,
                       const int* __restrict__ elen,
                       u16* __restrict__ qh, u16* __restrict__ kh,
                       u16* __restrict__ vth, float* __restrict__ vsum) {
  __shared__ u16 Sm[17408];  // K-loop: A@0, B@8192 ([128][64] f16 = 16 KB ea);
                             // epilogue: C tile [128][136] (34816 B)
  const int z = blockIdx.z;
  const int m0 = blockIdx.x * 128, n0 = blockIdx.y * 128;
  // R13 dead-row skip: Q/K rows >= len[batch] are never consumed downstream.
  if (z != 2 && (m0 & 1023) >= elen[m0 >> 10]) return;  // block-uniform

  const u16* wT = z == 0 ? wqT : (z == 1 ? wkT : wvT);
  const float* bias = z == 0 ? bq : (z == 1 ? bk : bv);
  u16* oh = z == 0 ? qh : (z == 1 ? kh : vth);
  const float oscale = (z == 0) ? 0.18033688011112042f : 1.0f;  // 0.125*log2(e)

  const int tid = threadIdx.x, l = tid & 63, w = tid >> 6;
  const int quad = l >> 4, col = l & 15;
  const int wm = (w & 1) * 64, wn = (w >> 1) * 64;

  const int row0 = tid >> 3, ch = tid & 7;
  const int sc8 = (ch ^ (row0 & 7)) * 8;
  int gofs[4], lofs[4];
#pragma unroll
  for (int p = 0; p < 4; p++) {
    gofs[p] = (row0 + 32 * p) * 1024 + sc8;
    lofs[p] = (tid + p * 256) * 8;
  }

  const u16* Ag = xh + m0 * 1024;
  const u16* Bg = wT + n0 * 1024;

  int ar[2][4], br[2][4];
#pragma unroll
  for (int ks = 0; ks < 2; ks++) {
#pragma unroll
    for (int i = 0; i < 4; i++) {
      int r = wm + i * 16 + col;
      ar[ks][i] = r * 64 + (((ks * 4 + quad) ^ (r & 7)) * 8);
    }
#pragma unroll
    for (int j = 0; j < 4; j++) {
      int r = wn + j * 16 + col;
      br[ks][j] = r * 64 + (((ks * 4 + quad) ^ (r & 7)) * 8);
    }
  }

  floatx4 zero4 = {0.f, 0.f, 0.f, 0.f};
  floatx4 acc[4][4];
#pragma unroll
  for (int i = 0; i < 4; i++)
#pragma unroll
    for (int j = 0; j < 4; j++) acc[i][j] = zero4;

  for (int k0 = 0; k0 < 1024; k0 += 64) {
    __syncthreads();  // previous compute done before LDS overwrite
#pragma unroll
    for (int p = 0; p < 4; p++) async_cp16(Sm + lofs[p], Ag + gofs[p] + k0);
#pragma unroll
    for (int p = 0; p < 4; p++)
      async_cp16(Sm + 8192 + lofs[p], Bg + gofs[p] + k0);
    __syncthreads();  // DMA drained

#pragma unroll
    for (int ks = 0; ks < 2; ks++) {
      half8 fa[4], fb[4];
#pragma unroll
      for (int i = 0; i < 4; i++) fa[i] = *(const half8*)(Sm + ar[ks][i]);
#pragma unroll
      for (int j = 0; j < 4; j++)
        fb[j] = *(const half8*)(Sm + 8192 + br[ks][j]);
#pragma unroll
      for (int i = 0; i < 4; i++)
#pragma unroll
        for (int j = 0; j < 4; j++) acc[i][j] = MFMA16(fa[i], fb[j], acc[i][j]);
    }
  }

  // ---- epilogue: stage C tile in LDS ([128][136]) for coalesced stores ----
  const int bidx = m0 >> 10;     // batch index
  const int sbase = m0 & 1023;
  __syncthreads();  // all K-loop LDS reads done before overwrite

#pragma unroll
  for (int j = 0; j < 4; j++) {
    int nloc = wn + j * 16 + col;
    float bb = bias[n0 + nloc];
#pragma unroll
    for (int i = 0; i < 4; i++)
#pragma unroll
      for (int r = 0; r < 4; r++) {
        int mloc = wm + i * 16 + quad * 4 + r;
        Sm[mloc * 136 + nloc] = f2h((acc[i][j][r] + bb) * oscale);
      }
  }
  __syncthreads();

  if (z != 2) {
    // q/k: [bh][s][64] -- row-contiguous 16B chunks
#pragma unroll
    for (int k = 0; k < 8; k++) {
      int c = tid + k * 256;
      int mloc = c >> 4, n = (c & 15) * 8;
      int hh = (n0 + n) >> 6, d = (n0 + n) & 63;
      half8 vv = *(const half8*)(Sm + mloc * 136 + n);
      *(half8*)(oh + ((bidx * 16 + hh) * 1024 + sbase + mloc) * 64 + d) = vv;
    }
  } else {
    // V^T: [bh][d][1024] -- transposed read, s-contiguous 16B stores
#pragma unroll
    for (int k = 0; k < 8; k++) {
      int c = tid + k * 256;
      int nloc = c & 127, s0 = (c >> 7) * 8;
      int hh = (n0 + nloc) >> 6, d = (n0 + nloc) & 63;
      u16 tmp[8];
#pragma unroll
      for (int e = 0; e < 8; e++) tmp[e] = Sm[(s0 + e) * 136 + nloc];
      *(half8*)(vth + ((bidx * 16 + hh) * 64 + d) * 1024 + sbase + s0) =
          *(half8*)tmp;
    }
    // vsum partials from fp32 acc: vsum[bh*64+d] += sum over this block's s
#pragma unroll
    for (int j = 0; j < 4; j++) {
      int nloc = wn + j * 16 + col;
      float bb = bias[n0 + nloc];
      float part = 16.0f * bb;
#pragma unroll
      for (int i = 0; i < 4; i++)
#pragma unroll
        for (int r = 0; r < 4; r++) part += acc[i][j][r];
      part += __shfl_xor(part, 16, 64);  // reduce across quads (same n)
      part += __shfl_xor(part, 32, 64);
      if (quad == 0) {
        int hh = (n0 + nloc) >> 6, d = (n0 + nloc) & 63;
        unsafeAtomicAdd(vsum + (bidx * 16 + hh) * 64 + d, part);
      }
    }
  }
}

// ---------------------------------------------------------------------------
// Swizzled tile stage for k_attn (512 threads): NC 64-row chunks of
// [rows][64] f16, global -> LDS via DMA, XOR bank swizzle on the src.
// ---------------------------------------------------------------------------
template <int NC>
__device__ __forceinline__ void stageN(u16* lds, const u16* g, int row_stride,
                                       int tid) {
#pragma unroll
  for (int p = 0; p < NC; p++) {
    int slot = (p * 512 + tid) * 8;  // element index; *2 = bytes
    int row = slot >> 6;
    int gp = (slot >> 3) & 7;
    int gl = gp ^ (row & 7);
    async_cp16(lds + slot, g + row * row_stride + gl * 8);
  }
}

// ---------------------------------------------------------------------------
// 3) flash attention, fp16, static softmax, in-register P (R18/R19).
//    512 thr = 8 waves: wave (qb=w>>1, th=w&1) owns q-block qb*32..+32 and
//    t-half th*32..+32 of each 64-t tile. Per iter per wave:
//      stage t+1 (2 cp16/thread)
//      S^T = K*Q: 4x MFMA32 (A=K rows t, B=Q cols q persistent in regs)
//        -> sc[16]: lane q=qb*32+(l&31), t = t0+th*32+(r&3)+8*(r>>2)+4*lh
//      mask (last tile), exp2 x16, f2h-pack x8
//      A-frag rebuild: 8x shfl_xor(32) + cndmask (lane^32 exchange)
//      PV: 4x MFMA32 into O0/O1 (d 0..31, 32..63)
//      __syncthreads (drains next-tile DMA; ONE barrier/iter)
//    Epilogue: th-pairs combine O via SCALAR osh[r*64+l] (R19 fix: r-rows
//    are stride-64, NOT memory-consecutive -- float4 across r raced lanes),
//    l via lsh, normalize, coalesced f32 stores (lane = d).
// ---------------------------------------------------------------------------
__launch_bounds__(512)
__global__ void k_attn(const u16* __restrict__ qh_g,
                       const u16* __restrict__ kh_g,
                       const u16* __restrict__ vth_g,
                       const float* __restrict__ vsum, const int* __restrict__ elen,
                       float* __restrict__ out) {
  __shared__ u16 QP[8192];       // Q [128][64] swizzled; floats reused for l
  __shared__ u16 Bufs[2][8192];  // per buf: K@0 [64][64], VT@4096 [64][64]
  const int tid = threadIdx.x, l = tid & 63, w = tid >> 6;  // w in 0..7
  const int l31 = l & 31, lh = l >> 5;
  const int qb = w >> 1;   // q-block (32 rows)
  const int th = w & 1;    // t-half (32 of 64 tile rows)
  // ---- balance remap (bijective on [0,512)): co-resident {id, id+256}
  //      differ in batch ----
  const int id = blockIdx.x;
  const int b = (id + (id >> 8)) & 3;
  const int h = (id >> 2) & 15;
  const int bh = b * 16 + h;
  const int q0 = ((id >> 6) & 7) * 128;
  const int len = elen[b];

  if (q0 >= len) {  // fully-invalid tile: uniform attention over ALL t (ref)
    float val = vsum[bh * 64 + l] * (1.0f / 1024.0f);
    float* op = out + (b * 1024 + q0) * 1024 + h * 64 + l;
    for (int r = w; r < 128; r += 8) op[r * 1024] = val;
    return;
  }

  const u16* kh_b  = kh_g + bh * 65536;
  const u16* vth_b = vth_g + bh * 65536;

  // prologue: stage Q (128 rows) + tile 0, full drain
  stageN<2>(QP, qh_g + (bh * 1024 + q0) * 64, 64, tid);
  stageN<1>(Bufs[0], kh_b, 64, tid);
  stageN<1>(Bufs[0] + 4096, vth_b, 1024, tid);
  __syncthreads();

  // persistent Q B-frags: col q = qb*32+l31, k = d (4 k-steps of 16)
  half8 qf[4];
  {
    int qrow = qb * 32 + l31;
#pragma unroll
    for (int kd = 0; kd < 4; kd++)
      qf[kd] = *(const half8*)(QP + qrow * 64 +
                               (((kd * 2 + lh) ^ (qrow & 7)) * 8));
  }
  // K A-frag offsets: row t = th*32+l31, k = d
  int kof[4];
  {
    int kr = th * 32 + l31;
#pragma unroll
    for (int kd = 0; kd < 4; kd++)
      kof[kd] = kr * 64 + (((kd * 2 + lh) ^ (kr & 7)) * 8);
  }
  // V B-frag offsets: col d = db*32+l31, k = t = th*32 + ks*16 + lh*8
  int vof[2][2];
#pragma unroll
  for (int ks = 0; ks < 2; ks++)
#pragma unroll
    for (int db = 0; db < 2; db++) {
      int vr = db * 32 + l31;
      int ch = th * 4 + ks * 2 + lh;
      vof[ks][db] = vr * 64 + ((ch ^ (vr & 7)) * 8);
    }

  f32x16 O0, O1;
#pragma unroll
  for (int r = 0; r < 16; r++) { O0[r] = 0.f; O1[r] = 0.f; }
  float lsum = 0.f;

  const int ntt = (len + 63) >> 6;
  for (int tt = 0; tt < ntt; ++tt) {
    const int t0 = tt * 64;
    u16* cur = Bufs[tt & 1];
    if (tt + 1 < ntt) {  // overlap: DMA tile t+1 while computing tile t
      u16* nxt = Bufs[(tt + 1) & 1];
      stageN<1>(nxt, kh_b + (t0 + 64) * 64, 64, tid);
      stageN<1>(nxt + 4096, vth_b + (t0 + 64), 1024, tid);
    }

    // ---- S^T = K Q (q carries 0.125*log2e) ----
    f32x16 sc;
#pragma unroll
    for (int r = 0; r < 16; r++) sc[r] = 0.f;
#pragma unroll
    for (int kd = 0; kd < 4; kd++) {
      half8 kf = *(const half8*)(cur + kof[kd]);
      sc = MFMA32(kf, qf[kd], sc);
    }

    if (t0 + 64 > len) {  // only the last partial tile masks
#pragma unroll
      for (int r = 0; r < 16; r++) {
        int t = t0 + th * 32 + (r & 3) + 8 * (r >> 2) + 4 * lh;
        if (t >= len) sc[r] = -3e38f;  // exp2 -> 0 (assignment kills NaN)
      }
    }

    // ---- static softmax: p = exp2(score), f16 RTN, packed in regs ----
    uint32_t pk[8];
#pragma unroll
    for (int i = 0; i < 8; i++) {
      float e0 = __builtin_exp2f(sc[2 * i]);
      float e1 = __builtin_exp2f(sc[2 * i + 1]);
      lsum += e0 + e1;
      pk[i] = (uint32_t)f2h(e0) | ((uint32_t)f2h(e1) << 16);
    }

    // ---- PV A-frag rebuild: lane^32 exchange (pk[i] = t {4lh+..} pairs;
    //      frag word j needs t {8lh + 2j, 8lh + 2j + 1}) ----
    union Frag { uint32_t u[4]; half8 h; };
    Frag pa[2];
#pragma unroll
    for (int ks = 0; ks < 2; ks++) {
      uint32_t p0 = pk[ks * 4 + 0], p1 = pk[ks * 4 + 1];
      uint32_t p2 = pk[ks * 4 + 2], p3 = pk[ks * 4 + 3];
      uint32_t x0 = (uint32_t)__shfl_xor((int)p0, 32, 64);
      uint32_t x1 = (uint32_t)__shfl_xor((int)p1, 32, 64);
      uint32_t x2 = (uint32_t)__shfl_xor((int)p2, 32, 64);
      uint32_t x3 = (uint32_t)__shfl_xor((int)p3, 32, 64);
      pa[ks].u[0] = lh ? x2 : p0;  // t {8lh+0, 8lh+1}
      pa[ks].u[1] = lh ? x3 : p1;  // t {8lh+2, 8lh+3}
      pa[ks].u[2] = lh ? p2 : x0;  // t {8lh+4, 8lh+5}
      pa[ks].u[3] = lh ? p3 : x1;  // t {8lh+6, 8lh+7}
    }

    // ---- O += P * V (k = wave's 32 t; d split 0..31 / 32..63) ----
#pragma unroll
    for (int ks = 0; ks < 2; ks++) {
      half8 vb0 = *(const half8*)(cur + 4096 + vof[ks][0]);
      O0 = MFMA32(pa[ks].h, vb0, O0);
      half8 vb1 = *(const half8*)(cur + 4096 + vof[ks][1]);
      O1 = MFMA32(pa[ks].h, vb1, O1);
    }

    __syncthreads();  // drain next-tile DMA + WAR on bufs (ONE barrier/iter)
  }

  // ---- epilogue: th-pair combine through freed LDS (SCALAR r-row I/O) ----
  float lw = lsum + __shfl_xor(lsum, 32, 64);  // lh halves -> l[q] per th
  float* lsh = (float*)QP;                      // 256 floats
  if (l < 32) lsh[th * 128 + qb * 32 + l] = lw;

  float* osh = (float*)Bufs;  // 8192 floats: slot (qb, r 0..31, lane)
  if (th) {
#pragma unroll
    for (int r = 0; r < 16; r++) {
      osh[qb * 2048 + r * 64 + l] = O0[r];          // R19: scalar, stride-64
      osh[qb * 2048 + (16 + r) * 64 + l] = O1[r];
    }
  }
  __syncthreads();
  if (th) return;

#pragma unroll
  for (int r = 0; r < 16; r++) {
    O0[r] += osh[qb * 2048 + r * 64 + l];
    O1[r] += osh[qb * 2048 + (16 + r) * 64 + l];
  }

  const float vs0 = vsum[bh * 64 + l31] * (1.0f / 1024.0f);
  const float vs1 = vsum[bh * 64 + 32 + l31] * (1.0f / 1024.0f);
#pragma unroll
  for (int g = 0; g < 4; g++) {
    int qbase = qb * 32 + 8 * g + 4 * lh;       // q for r = g*4 + i
    float4 la = *(const float4*)(lsh + qbase);         // th=0 partial
    float4 lb = *(const float4*)(lsh + 128 + qbase);   // th=1 partial
#pragma unroll
    for (int i = 0; i < 4; i++) {
      int s = q0 + qbase + i;
      float lr = (&la.x)[i] + (&lb.x)[i];
      float invl = 1.0f / lr;
      bool valid = (s < len);
      int r = g * 4 + i;
      float v0 = valid ? O0[r] * invl : vs0;
      float v1 = valid ? O1[r] * invl : vs1;
      float* op = out + (b * 1024 + s) * 1024 + h * 64 + l31;
      op[0]  = v0;
      op[32] = v1;
    }
  }
}

// ---------------------------------------------------------------------------
// launch
// ---------------------------------------------------------------------------
extern "C" void kernel_launch(void* const* d_in, const int* in_sizes, int n_in,
                              void* d_out, int out_size, void* d_ws, size_t ws_size,
                              hipStream_t stream) {
  (void)in_sizes; (void)n_in; (void)out_size; (void)ws_size;
  const float* x  = (const float*)d_in[0];
  const float* Wq = (const float*)d_in[1];
  const float* bq = (const float*)d_in[2];
  const float* Wk = (const float*)d_in[3];
  const float* bk = (const float*)d_in[4];
  const float* Wv = (const float*)d_in[5];
  const float* bv = (const float*)d_in[6];
  const int* elen = (const int*)d_in[7];
  float* out = (float*)d_out;

  char* ws = (char*)d_ws;
  const size_t MB = 1024 * 1024;
  u16* xh  = (u16*)(ws + 0 * MB);
  u16* wqT = (u16*)(ws + 8 * MB);
  u16* wkT = (u16*)(ws + 10 * MB);
  u16* wvT = (u16*)(ws + 12 * MB);
  u16* qh  = (u16*)(ws + 14 * MB);
  u16* kh  = (u16*)(ws + 22 * MB);
  u16* vth = (u16*)(ws + 30 * MB);
  float* vsum = (float*)(ws + 38 * MB);  // 4096 floats

  k_prep<<<7168, 256, 0, stream>>>(x, xh, Wq, Wk, Wv, wqT, wkT, wvT, vsum);
  k_proj<<<dim3(32, 8, 3), 256, 0, stream>>>(xh, wqT, wkT, wvT, bq, bk, bv,
                                             elen, qh, kh, vth, vsum);
  k_attn<<<512, 512, 0, stream>>>(qh, kh, vth, vsum, elen, out);
}

// Round 9
// 149.023 us; speedup vs baseline: 1.0185x; 1.0185x over previous
//
#include <hip/hip_runtime.h>
#include <stdint.h>

// ---------------------------------------------------------------------------
// MultiAttentionHead: B=4 S=1024 E=1024 H=16 D=64, fp32 in/out.
// R20: REVERT to measured-best (R15/R17 source, 147.3/148.7us). R19's
// in-register P passed but regressed +3us: the exp2->f2h->shfl_xor->cndmask
// chain sits ON the critical path between QK and PV MFMAs, and at 2 blk/CU
// there are too few independent waves to hide it. Together with R12 (LDS
// instr halved: null), VERDICT: k_attn is latency-bound, NOT LDS-issue-
// bound; LDS-traffic levers don't move it. Ledger: proj at m97 ceiling
// (8-phase grid-starved at 192 blocks; R9/R16 loop rejects edits), prep at
// HBM BW, attn latency-bound (R12/R14/R18 all null/negative), ~87us fills
// fixed. Decomposition at practical floor.
// R15: k_attn QBLK=128 (512 thr, 8 waves), K/V staged once per 128 q.
// R13: k_proj dead-row skip for Q/K (sbase>=len early-return).
// R12: swapped QK^T (S^T=K*Q), K as A-operand, persistent Q B-frags,
// packed ds_write_b64 P, mid-iter lgkmcnt-only barrier.
// Carried: R1 XOR swizzle (0 conflicts), R4 static softmax, R7 dbuf,
// R8 LDS epilogue + direct V^T, R10 all-fp16, R11 batch-balance remap.
// R9/R14/R16/R19 post-mortems: 2-barrier loops reject dbuf/counted-vmcnt/
// intra-loop branching/in-reg-P -- compiler's own schedule is the asset.
// ---------------------------------------------------------------------------

using u16     = unsigned short;
using half8   = __attribute__((ext_vector_type(8))) _Float16;
using floatx4 = __attribute__((ext_vector_type(4))) float;

#define MFMA16(a, b, c) __builtin_amdgcn_mfma_f32_16x16x32_f16(a, b, c, 0, 0, 0)

__device__ __forceinline__ u16 f2h(float f) {  // f32 -> f16 bits (RTN)
  _Float16 h = (_Float16)f; u16 u; __builtin_memcpy(&u, &h, 2); return u;
}

// async global->LDS DMA, 16B per lane. LDS dest must be wave-uniform base +
// lane*16 (no per-lane scatter) -- so bank swizzles permute the GLOBAL src.
__device__ __forceinline__ void async_cp16(void* lds, const void* g) {
  __builtin_amdgcn_global_load_lds(
      (__attribute__((address_space(1))) uint32_t*)(uintptr_t)g,
      (__attribute__((address_space(3))) uint32_t*)(uint32_t)(uintptr_t)lds,
      16, 0, 0);
}

// ---------------------------------------------------------------------------
// 1) prep (fused): blocks [0,4096): x -> f16 (block 0 zeroes vsum);
//    blocks [4096,7168): transpose W -> WT[n][k] f16.
// ---------------------------------------------------------------------------
__global__ void k_prep(const float* __restrict__ x, u16* __restrict__ xh,
                       const float* __restrict__ w0, const float* __restrict__ w1,
                       const float* __restrict__ w2,
                       u16* __restrict__ o0, u16* __restrict__ o1,
                       u16* __restrict__ o2, float* __restrict__ vsum) {
  __shared__ float t[32][33];
  const int bx = blockIdx.x;
  if (bx < 4096) {
    int i = (bx * 256 + threadIdx.x) * 4;
    float4 v = *(const float4*)(x + i);
    ushort4 hv;
    hv.x = f2h(v.x);
    hv.y = f2h(v.y);
    hv.z = f2h(v.z);
    hv.w = f2h(v.w);
    *(ushort4*)(xh + i) = hv;
    if (bx == 0) {  // zero vsum (4096 floats) for k_proj's atomics
      float4 z = {0.f, 0.f, 0.f, 0.f};
#pragma unroll
      for (int e = 0; e < 4; e++) ((float4*)vsum)[threadIdx.x * 4 + e] = z;
    }
    return;
  }
  const int id = bx - 4096;                 // 0..3071
  const int z = id >> 10, rem = id & 1023;
  const float* W = z == 0 ? w0 : (z == 1 ? w1 : w2);
  u16* oh = z == 0 ? o0 : (z == 1 ? o1 : o2);
  const int kb = (rem & 31) * 32, nb = (rem >> 5) * 32;
  const int tx = threadIdx.x & 31, ty = threadIdx.x >> 5;
  for (int r = ty; r < 32; r += 8) t[r][tx] = W[(kb + r) * 1024 + nb + tx];
  __syncthreads();
  for (int r = ty; r < 32; r += 8)
    oh[(nb + r) * 1024 + kb + tx] = f2h(t[tx][r]);
}

// ---------------------------------------------------------------------------
// 2) projection GEMM: C[4096][1024] = xh @ Wh + b, fp16 single pass,
//    128x128 tile, BK=64, 2-barrier K-loop (R9: dbuf regresses here).
//    LDS 32 KB staging / 34.8 KB epilogue tile -> 4 blocks/CU. Epilogue
//    stages C through LDS ([128][136]) for 16B stores. z=0/1 -> q/k f16 in
//    [B][H][S][D] (q pre-scaled by 0.125*log2e); z=2 -> V^T f16 + vsum.
//    R13: z=0/1 blocks whose 128 s-rows are all >= len[b] early-return.
// ---------------------------------------------------------------------------
__launch_bounds__(256, 4)
__global__ void k_proj(const u16* __restrict__ xh,
                       const u16* __restrict__ wqT, const u16* __restrict__ wkT,
                       const u16* __restrict__ wvT,
                       const float* __restrict__ bq, const float* __restrict__ bk,
                       const float* __restrict__ bv,
                       const int* __restrict__ elen,
                       u16* __restrict__ qh, u16* __restrict__ kh,
                       u16* __restrict__ vth, float* __restrict__ vsum) {
  __shared__ u16 Sm[17408];  // K-loop: A@0, B@8192 ([128][64] f16 = 16 KB ea);
                             // epilogue: C tile [128][136] (34816 B)
  const int z = blockIdx.z;
  const int m0 = blockIdx.x * 128, n0 = blockIdx.y * 128;
  // R13 dead-row skip: Q/K rows >= len[batch] are never consumed downstream.
  if (z != 2 && (m0 & 1023) >= elen[m0 >> 10]) return;  // block-uniform

  const u16* wT = z == 0 ? wqT : (z == 1 ? wkT : wvT);
  const float* bias = z == 0 ? bq : (z == 1 ? bk : bv);
  u16* oh = z == 0 ? qh : (z == 1 ? kh : vth);
  const float oscale = (z == 0) ? 0.18033688011112042f : 1.0f;  // 0.125*log2(e)

  const int tid = threadIdx.x, l = tid & 63, w = tid >> 6;
  const int quad = l >> 4, col = l & 15;
  const int wm = (w & 1) * 64, wn = (w >> 1) * 64;

  const int row0 = tid >> 3, ch = tid & 7;
  const int sc8 = (ch ^ (row0 & 7)) * 8;
  int gofs[4], lofs[4];
#pragma unroll
  for (int p = 0; p < 4; p++) {
    gofs[p] = (row0 + 32 * p) * 1024 + sc8;
    lofs[p] = (tid + p * 256) * 8;
  }

  const u16* Ag = xh + m0 * 1024;
  const u16* Bg = wT + n0 * 1024;

  int ar[2][4], br[2][4];
#pragma unroll
  for (int ks = 0; ks < 2; ks++) {
#pragma unroll
    for (int i = 0; i < 4; i++) {
      int r = wm + i * 16 + col;
      ar[ks][i] = r * 64 + (((ks * 4 + quad) ^ (r & 7)) * 8);
    }
#pragma unroll
    for (int j = 0; j < 4; j++) {
      int r = wn + j * 16 + col;
      br[ks][j] = r * 64 + (((ks * 4 + quad) ^ (r & 7)) * 8);
    }
  }

  floatx4 zero4 = {0.f, 0.f, 0.f, 0.f};
  floatx4 acc[4][4];
#pragma unroll
  for (int i = 0; i < 4; i++)
#pragma unroll
    for (int j = 0; j < 4; j++) acc[i][j] = zero4;

  for (int k0 = 0; k0 < 1024; k0 += 64) {
    __syncthreads();  // previous compute done before LDS overwrite
#pragma unroll
    for (int p = 0; p < 4; p++) async_cp16(Sm + lofs[p], Ag + gofs[p] + k0);
#pragma unroll
    for (int p = 0; p < 4; p++)
      async_cp16(Sm + 8192 + lofs[p], Bg + gofs[p] + k0);
    __syncthreads();  // DMA drained

#pragma unroll
    for (int ks = 0; ks < 2; ks++) {
      half8 fa[4], fb[4];
#pragma unroll
      for (int i = 0; i < 4; i++) fa[i] = *(const half8*)(Sm + ar[ks][i]);
#pragma unroll
      for (int j = 0; j < 4; j++)
        fb[j] = *(const half8*)(Sm + 8192 + br[ks][j]);
#pragma unroll
      for (int i = 0; i < 4; i++)
#pragma unroll
        for (int j = 0; j < 4; j++) acc[i][j] = MFMA16(fa[i], fb[j], acc[i][j]);
    }
  }

  // ---- epilogue: stage C tile in LDS ([128][136]) for coalesced stores ----
  const int bidx = m0 >> 10;     // batch index
  const int sbase = m0 & 1023;
  __syncthreads();  // all K-loop LDS reads done before overwrite

#pragma unroll
  for (int j = 0; j < 4; j++) {
    int nloc = wn + j * 16 + col;
    float bb = bias[n0 + nloc];
#pragma unroll
    for (int i = 0; i < 4; i++)
#pragma unroll
      for (int r = 0; r < 4; r++) {
        int mloc = wm + i * 16 + quad * 4 + r;
        Sm[mloc * 136 + nloc] = f2h((acc[i][j][r] + bb) * oscale);
      }
  }
  __syncthreads();

  if (z != 2) {
    // q/k: [bh][s][64] -- row-contiguous 16B chunks
#pragma unroll
    for (int k = 0; k < 8; k++) {
      int c = tid + k * 256;
      int mloc = c >> 4, n = (c & 15) * 8;
      int hh = (n0 + n) >> 6, d = (n0 + n) & 63;
      half8 vv = *(const half8*)(Sm + mloc * 136 + n);
      *(half8*)(oh + ((bidx * 16 + hh) * 1024 + sbase + mloc) * 64 + d) = vv;
    }
  } else {
    // V^T: [bh][d][1024] -- transposed read, s-contiguous 16B stores
#pragma unroll
    for (int k = 0; k < 8; k++) {
      int c = tid + k * 256;
      int nloc = c & 127, s0 = (c >> 7) * 8;
      int hh = (n0 + nloc) >> 6, d = (n0 + nloc) & 63;
      u16 tmp[8];
#pragma unroll
      for (int e = 0; e < 8; e++) tmp[e] = Sm[(s0 + e) * 136 + nloc];
      *(half8*)(vth + ((bidx * 16 + hh) * 64 + d) * 1024 + sbase + s0) =
          *(half8*)tmp;
    }
    // vsum partials from fp32 acc: vsum[bh*64+d] += sum over this block's s
#pragma unroll
    for (int j = 0; j < 4; j++) {
      int nloc = wn + j * 16 + col;
      float bb = bias[n0 + nloc];
      float part = 16.0f * bb;
#pragma unroll
      for (int i = 0; i < 4; i++)
#pragma unroll
        for (int r = 0; r < 4; r++) part += acc[i][j][r];
      part += __shfl_xor(part, 16, 64);  // reduce across quads (same n)
      part += __shfl_xor(part, 32, 64);
      if (quad == 0) {
        int hh = (n0 + nloc) >> 6, d = (n0 + nloc) & 63;
        unsafeAtomicAdd(vsum + (bidx * 16 + hh) * 64 + d, part);
      }
    }
  }
}

// ---------------------------------------------------------------------------
// Swizzled tile stage for k_attn (512 threads): NC 64-row chunks of
// [rows][64] f16, global -> LDS via DMA, XOR bank swizzle on the src.
// ---------------------------------------------------------------------------
template <int NC>
__device__ __forceinline__ void stageN(u16* lds, const u16* g, int row_stride,
                                       int tid) {
#pragma unroll
  for (int p = 0; p < NC; p++) {
    int slot = (p * 512 + tid) * 8;  // element index; *2 = bytes
    int row = slot >> 6;
    int gp = (slot >> 3) & 7;
    int gl = gp ^ (row & 7);
    async_cp16(lds + slot, g + row * row_stride + gl * 8);
  }
}

// ---------------------------------------------------------------------------
// 3) flash attention, fp16, static softmax, double-buffered staging.
//    R15: QBLK=128, 512 threads (8 waves), grid 512 = 64 bh x 8 q-blocks.
//    K/V staged once per 128 q (traffic & barriers halved per unit work).
//    Wave roles: QK -> (t-block tb=w&3, q-half qh2=w>>2); PV -> q-block w.
//    Loop (R13 sync): stage t+1 (2 cp16/thread); QK 8 MFMA; mask; softmax
//    (16 exp2, 4x ds_write_b64 P); lgkmcnt(0)+s_barrier (DMA in flight);
//    PV 8 MFMA; __syncthreads.
// ---------------------------------------------------------------------------
__launch_bounds__(512)
__global__ void k_attn(const u16* __restrict__ qh_g,
                       const u16* __restrict__ kh_g,
                       const u16* __restrict__ vth_g,
                       const float* __restrict__ vsum, const int* __restrict__ elen,
                       float* __restrict__ out) {
  __shared__ u16 QP[8192];       // [128][64] swizzled: Q, then P (aliased)
  __shared__ u16 Bufs[2][8192];  // per buf: K@0 [64][64], VT@4096 [64][64]
  const int tid = threadIdx.x, l = tid & 63, w = tid >> 6;  // w in 0..7
  const int quad = l >> 4, col = l & 15;
  const int tb = w & 3;    // QK t-block
  const int qh2 = w >> 2;  // QK q-half (jq base = qh2*4)
  // ---- balance remap (bijective on [0,512)): co-resident {id, id+256}
  //      differ in batch; same-bh q-blocks are 64 apart -> same XCD ----
  const int id = blockIdx.x;
  const int b = (id + (id >> 8)) & 3;
  const int h = (id >> 2) & 15;
  const int bh = b * 16 + h;
  const int q0 = ((id >> 6) & 7) * 128;
  const int len = elen[b];

  if (q0 >= len) {  // fully-invalid tile: uniform attention over ALL t (ref)
    float val = vsum[bh * 64 + l] * (1.0f / 1024.0f);
    float* op = out + (b * 1024 + q0) * 1024 + h * 64 + l;
    for (int r = w; r < 128; r += 8) op[r * 1024] = val;
    return;
  }

  const u16* kh_b  = kh_g + bh * 65536;
  const u16* vth_b = vth_g + bh * 65536;

  // prologue: stage Q (128 rows) + tile 0, full drain
  stageN<2>(QP, qh_g + (bh * 1024 + q0) * 64, 64, tid);
  stageN<1>(Bufs[0], kh_b, 64, tid);
  stageN<1>(Bufs[0] + 4096, vth_b, 1024, tid);
  __syncthreads();

  // persistent Q as B-operand fragments: qf[jj][ks], row = (qh2*4+jj)*16+col
  half8 qf[4][2];
#pragma unroll
  for (int jj = 0; jj < 4; jj++) {
    int qrow = (qh2 * 4 + jj) * 16 + col;
#pragma unroll
    for (int ks = 0; ks < 2; ks++)
      qf[jj][ks] = *(const half8*)(QP + qrow * 64 +
                                   (((ks * 4 + quad) ^ (qrow & 7)) * 8));
  }
  __syncthreads();  // ALL Q reads done before any P write (QP aliased)

  // K A-frag offsets: row = tb*16 + col (t)
  int ko[2];
#pragma unroll
  for (int ks = 0; ks < 2; ks++) {
    int r = tb * 16 + col;
    ko[ks] = r * 64 + (((ks * 4 + quad) ^ (r & 7)) * 8);
  }
  // P A-frag offsets: row = w*16 + col (q, 0..127)
  int po[2];
#pragma unroll
  for (int ks = 0; ks < 2; ks++) {
    int r = w * 16 + col;
    po[ks] = r * 64 + (((ks * 4 + quad) ^ (r & 7)) * 8);
  }
  // V B-frag offsets (n = j*16 + col = d)
  int kvo[2][4];
#pragma unroll
  for (int ks = 0; ks < 2; ks++)
#pragma unroll
    for (int j = 0; j < 4; j++) {
      int n = j * 16 + col;
      kvo[ks][j] = n * 64 + (((ks * 4 + quad) ^ (n & 7)) * 8);
    }
  // packed P write offsets: row = (qh2*4+jj)*16+col, t-chunk = tb*2+(quad>>1)
  int p_wr[4];
  {
    int chv = tb * 2 + (quad >> 1);
#pragma unroll
    for (int jj = 0; jj < 4; jj++) {
      int row = (qh2 * 4 + jj) * 16 + col;
      p_wr[jj] = row * 64 + ((chv ^ (row & 7)) * 8) + (quad & 1) * 4;
    }
  }

  floatx4 zero4 = {0.f, 0.f, 0.f, 0.f};
  floatx4 O[4];
  float lp[4];  // per-thread l partials over this thread's t-slice
#pragma unroll
  for (int j = 0; j < 4; j++) O[j] = zero4;
#pragma unroll
  for (int jj = 0; jj < 4; jj++) lp[jj] = 0.f;

  const int ntt = (len + 63) >> 6;
  for (int tt = 0; tt < ntt; ++tt) {
    const int t0 = tt * 64;
    u16* cur = Bufs[tt & 1];
    if (tt + 1 < ntt) {  // overlap: DMA tile t+1 while computing tile t
      u16* nxt = Bufs[(tt + 1) & 1];
      const int t1 = t0 + 64;
      stageN<1>(nxt, kh_b + t1 * 64, 64, tid);
      stageN<1>(nxt + 4096, vth_b + t1, 1024, tid);
    }

    // ---- S^T = K Q (q carries 0.125*log2e); sc[jj][r]:
    //      q = (qh2*4+jj)*16 + col, t = t0 + tb*16 + quad*4 + r ----
    floatx4 sc[4];
#pragma unroll
    for (int jj = 0; jj < 4; jj++) sc[jj] = zero4;
#pragma unroll
    for (int ks = 0; ks < 2; ks++) {
      half8 kf = *(const half8*)(cur + ko[ks]);
#pragma unroll
      for (int jj = 0; jj < 4; jj++) sc[jj] = MFMA16(kf, qf[jj][ks], sc[jj]);
    }

    if (t0 + 64 > len) {  // only the last partial tile masks (t-cols >= len)
#pragma unroll
      for (int r = 0; r < 4; r++) {
        bool inv = (t0 + tb * 16 + quad * 4 + r) >= len;
#pragma unroll
        for (int jj = 0; jj < 4; jj++)
          if (inv) sc[jj][r] = -3e38f;  // exp2 -> 0 (assignment kills NaN)
      }
    }

    // ---- static softmax: p = exp2(score), f16 RTN, packed b64 writes ----
#pragma unroll
    for (int jj = 0; jj < 4; jj++) {
      float e0 = __builtin_exp2f(sc[jj][0]);
      float e1 = __builtin_exp2f(sc[jj][1]);
      float e2 = __builtin_exp2f(sc[jj][2]);
      float e3 = __builtin_exp2f(sc[jj][3]);
      lp[jj] += (e0 + e1) + (e2 + e3);
      uint2 pk;
      pk.x = (uint32_t)f2h(e0) | ((uint32_t)f2h(e1) << 16);
      pk.y = (uint32_t)f2h(e2) | ((uint32_t)f2h(e3) << 16);
      *(uint2*)(QP + p_wr[jj]) = pk;  // 4 consecutive t -> one ds_write_b64
    }

    // P handoff: waves exchange slices. lgkmcnt only -- the tile t+1 DMA
    // (vmcnt) stays in flight across this barrier.
    asm volatile("s_waitcnt lgkmcnt(0)" ::: "memory");
    __builtin_amdgcn_s_barrier();
    __builtin_amdgcn_sched_barrier(0);

    // ---- O += P * V (wave w owns q-block w) ----
#pragma unroll
    for (int ks = 0; ks < 2; ks++) {
      half8 pa = *(const half8*)(QP + po[ks]);
#pragma unroll
      for (int j = 0; j < 4; j++) {
        half8 vb = *(const half8*)(cur + 4096 + kvo[ks][j]);
        O[j] = MFMA16(pa, vb, O[j]);
      }
    }

    __syncthreads();  // drain next-tile DMA + WAR on P before next softmax
  }

  // ---- epilogue: cross-wave l reduction through (now free) Bufs ----
  float* lred = (float*)Bufs;  // [4 tb][128 q] partials
#pragma unroll
  for (int jj = 0; jj < 4; jj++) {
    float v = lp[jj];
    v += __shfl_xor(v, 16, 64);  // sum over quads (wave's 16-t slice, all tt)
    v += __shfl_xor(v, 32, 64);
    lp[jj] = v;
  }
  if (quad == 0) {
#pragma unroll
    for (int jj = 0; jj < 4; jj++)
      lred[tb * 128 + (qh2 * 4 + jj) * 16 + col] = lp[jj];
  }
  __syncthreads();

#pragma unroll
  for (int r = 0; r < 4; r++) {
    int qloc = w * 16 + quad * 4 + r;
    int s = q0 + qloc;
    float lr = (lred[qloc] + lred[128 + qloc]) +
               (lred[256 + qloc] + lred[384 + qloc]);
    float invl = 1.0f / lr;
    bool valid = (s < len);
#pragma unroll
    for (int j = 0; j < 4; j++) {
      int d = j * 16 + col;
      float val = valid ? O[j][r] * invl : vsum[bh * 64 + d] * (1.0f / 1024.0f);
      out[(b * 1024 + s) * 1024 + h * 64 + d] = val;
    }
  }
}

// ---------------------------------------------------------------------------
// launch
// ---------------------------------------------------------------------------
extern "C" void kernel_launch(void* const* d_in, const int* in_sizes, int n_in,
                              void* d_out, int out_size, void* d_ws, size_t ws_size,
                              hipStream_t stream) {
  (void)in_sizes; (void)n_in; (void)out_size; (void)ws_size;
  const float* x  = (const float*)d_in[0];
  const float* Wq = (const float*)d_in[1];
  const float* bq = (const float*)d_in[2];
  const float* Wk = (const float*)d_in[3];
  const float* bk = (const float*)d_in[4];
  const float* Wv = (const float*)d_in[5];
  const float* bv = (const float*)d_in[6];
  const int* elen = (const int*)d_in[7];
  float* out = (float*)d_out;

  char* ws = (char*)d_ws;
  const size_t MB = 1024 * 1024;
  u16* xh  = (u16*)(ws + 0 * MB);
  u16* wqT = (u16*)(ws + 8 * MB);
  u16* wkT = (u16*)(ws + 10 * MB);
  u16* wvT = (u16*)(ws + 12 * MB);
  u16* qh  = (u16*)(ws + 14 * MB);
  u16* kh  = (u16*)(ws + 22 * MB);
  u16* vth = (u16*)(ws + 30 * MB);
  float* vsum = (float*)(ws + 38 * MB);  // 4096 floats

  k_prep<<<7168, 256, 0, stream>>>(x, xh, Wq, Wk, Wv, wqT, wkT, wvT, vsum);
  k_proj<<<dim3(32, 8, 3), 256, 0, stream>>>(xh, wqT, wkT, wvT, bq, bk, bv,
                                             elen, qh, kh, vth, vsum);
  k_attn<<<512, 512, 0, stream>>>(qh, kh, vth, vsum, elen, out);
}